// Round 2
// baseline (24.269 us; speedup 1.0000x reference)
//
#include <hip/hip_runtime.h>
#include <math.h>

// BeliefPropagation collapse (see round-0 derivation):
// h ∈ {0,1} is used as an INDEX by the reference, so only rows/cols 0,1 of the
// message matrices are live; the iteration is a 12-scalar recurrence driven by
// cnt1[v] = sum_e h[e,v], n1[c] = sum_j h[c,j] (c∈{0,1}), base, w[:,0:2], sign.
//
// Round-1 structure: two kernels.
//   k1: 32 blocks × 256 thr — int4-vectorized column counts of h, per-block
//       partials into d_ws (block-major, no atomics → no zeroing needed).
//   k2: 1 block × 1024 thr — reduce partials (64 KB, L2-hot), shuffle-reduce
//       rows 0,1 of h, thread-0 scalar recurrence, write out[512].

#define V_N 512
#define E_N 256
#define BLK1 32            // k1 blocks; each handles E_N/BLK1 = 8 rows

__device__ inline float ipowf_(float x, int n) {
    float r = 1.0f, p = x;
    while (n > 0) {
        if (n & 1) r *= p;
        p *= p;
        n >>= 1;
    }
    return r;
}

__global__ __launch_bounds__(256) void bp_count(const int* __restrict__ h,
                                                int* __restrict__ ws) {
    const int b = blockIdx.x, t = threadIdx.x;
    const int cg = t & 127;          // column group: cols 4cg..4cg+3
    const int rh = t >> 7;           // row half within block: 4 rows each
    const int4* h4 = (const int4*)h; // [E_N][V_N/4]
    const int rowbase = b * 8 + rh * 4;
    int4 acc = make_int4(0, 0, 0, 0);
    #pragma unroll
    for (int r = 0; r < 4; ++r) {
        int4 x = h4[(rowbase + r) * (V_N / 4) + cg];
        acc.x += x.x; acc.y += x.y; acc.z += x.z; acc.w += x.w;
    }
    __shared__ int4 p[2][128];
    p[rh][cg] = acc;
    __syncthreads();
    if (t < 128) {
        int4 a = p[0][t], c = p[1][t];
        ((int4*)ws)[b * 128 + t] =
            make_int4(a.x + c.x, a.y + c.y, a.z + c.z, a.w + c.w);
    }
}

__global__ __launch_bounds__(1024) void bp_solve(
    const float* __restrict__ l_v, const int* __restrict__ h,
    const float* __restrict__ s_c, const float* __restrict__ b,
    const float* __restrict__ w, const int* __restrict__ it_p,
    const int* __restrict__ ws, float* __restrict__ out)
{
    const int t = threadIdx.x;
    const int v = t & (V_N - 1);
    const int half = t >> 9;

    __shared__ int cntsh[1024];
    __shared__ int wred[16][2];
    __shared__ float csh[8];

    // ---- combine k1 partials: cnt1[v] = sum_b ws[b*512+v] (coalesced, L2-hot)
    int part = 0;
    #pragma unroll
    for (int bb = 0; bb < BLK1 / 2; ++bb)
        part += ws[(half * (BLK1 / 2) + bb) * V_N + v];
    cntsh[t] = part;

    // ---- row sums n1[0], n1[1]: rows 0,1 of h = h[0..1023]; wave-shuffle reduce
    int r0 = 0, r1 = 0;
    if (half == 0) { r0 = h[v]; r1 = h[V_N + v]; }
    #pragma unroll
    for (int off = 32; off > 0; off >>= 1) {
        r0 += __shfl_down(r0, off);
        r1 += __shfl_down(r1, off);
    }
    if ((t & 63) == 0) { wred[t >> 6][0] = r0; wred[t >> 6][1] = r1; }
    __syncthreads();

    // ---- 12-scalar recurrence (thread 0)
    if (t == 0) {
        int n1_0 = 0, n1_1 = 0;
        #pragma unroll
        for (int wv = 0; wv < 8; ++wv) { n1_0 += wred[wv][0]; n1_1 += wred[wv][1]; }
        const int iters = it_p[0];
        const int n0_0 = V_N - n1_0, n0_1 = V_N - n1_1;
        const int cnt1_0 = cntsh[0] + cntsh[V_N + 0];
        const int cnt1_1 = cntsh[1] + cntsh[V_N + 1];
        const int cnt0_0 = E_N - cnt1_0, cnt0_1 = E_N - cnt1_1;
        const float base0 = l_v[0] * b[0];
        const float base1 = l_v[1] * b[1];
        const float w00 = w[0],     w01 = w[1];          // w[0,0], w[0,1]
        const float w10 = w[E_N],   w11 = w[E_N + 1];    // w[1,0], w[1,1]
        const float sg0 = 1.0f - 2.0f * s_c[0];
        const float sg1 = 1.0f - 2.0f * s_c[1];

        float V0c0 = 0.f, V0c1 = 0.f, V1c0 = 0.f, V1c1 = 0.f;
        float C0v0 = 0.f, C0v1 = 0.f, C0vR = 0.f;
        float C1v0 = 0.f, C1v1 = 0.f, C1vR = 0.f;

        for (int it = 0; it < iters; ++it) {
            // v->c (reads OLD mu_cv); tot - T0 = T1 exactly
            float T0 = (float)cnt0_0 * C0v0 * w00;
            float T1 = (float)cnt1_0 * C1v0 * w01;
            float nV0c0 = tanhf(0.5f * (base0 + T1));
            float nV0c1 = tanhf(0.5f * (base0 + T0));
            T0 = (float)cnt0_1 * C0v1 * w10;
            T1 = (float)cnt1_1 * C1v1 * w11;
            float nV1c0 = tanhf(0.5f * (base1 + T1));
            float nV1c1 = tanhf(0.5f * (base1 + T0));

            // c->v (reads OLD mu_vc — Jacobi, matches reference)
            float t0 = tanhf(0.5f * V0c0);
            float t1 = tanhf(0.5f * V1c0);
            float p0 = ipowf_(t0, n0_0);
            float p1 = ipowf_(t1, n1_0);
            float nC0v0 = sg0 * 2.0f * atanhf(p1);
            float nC0v1 = sg0 * 2.0f * atanhf(p0);
            float nC0vR = sg0 * 2.0f * atanhf(p0 * p1);
            t0 = tanhf(0.5f * V0c1);
            t1 = tanhf(0.5f * V1c1);
            p0 = ipowf_(t0, n0_1);
            p1 = ipowf_(t1, n1_1);
            float nC1v0 = sg1 * 2.0f * atanhf(p1);
            float nC1v1 = sg1 * 2.0f * atanhf(p0);
            float nC1vR = sg1 * 2.0f * atanhf(p0 * p1);

            V0c0 = nV0c0; V0c1 = nV0c1; V1c0 = nV1c0; V1c1 = nV1c1;
            C0v0 = nC0v0; C0v1 = nC0v1; C0vR = nC0vR;
            C1v0 = nC1v0; C1v1 = nC1v1; C1vR = nC1vR;
        }
        csh[0] = C0v0; csh[1] = C0v1; csh[2] = C0vR;
        csh[3] = C1v0; csh[4] = C1v1; csh[5] = C1vR;
    }
    __syncthreads();

    // ---- marginalization + output
    if (half == 0) {
        const int cnt1 = cntsh[v] + cntsh[V_N + v];
        const int cnt0 = E_N - cnt1;
        const float basev = l_v[v] * b[v];
        const float wv0 = w[v * E_N + 0];
        const float wv1 = w[v * E_N + 1];
        const float c0 = (v == 0) ? csh[0] : (v == 1) ? csh[1] : csh[2];
        const float c1 = (v == 0) ? csh[3] : (v == 1) ? csh[4] : csh[5];
        const float s = basev + (float)cnt0 * c0 * wv0 + (float)cnt1 * c1 * wv1;
        const float mu = tanhf(0.5f * s);
        out[v] = 1.0f / (expf(mu) + 1.0f);
    }
}

extern "C" void kernel_launch(void* const* d_in, const int* in_sizes, int n_in,
                              void* d_out, int out_size, void* d_ws, size_t ws_size,
                              hipStream_t stream) {
    const float* l_v   = (const float*)d_in[0];
    const int*   h     = (const int*)  d_in[1];
    const float* s_c   = (const float*)d_in[2];
    const float* b     = (const float*)d_in[3];
    const float* w     = (const float*)d_in[4];
    const int*   iters = (const int*)  d_in[5];
    float* out = (float*)d_out;
    int*   ws  = (int*)d_ws;

    hipLaunchKernelGGL(bp_count, dim3(BLK1), dim3(256), 0, stream, h, ws);
    hipLaunchKernelGGL(bp_solve, dim3(1), dim3(1024), 0, stream,
                       l_v, h, s_c, b, w, iters, ws, out);
}

// Round 3
// 23.025 us; speedup vs baseline: 1.0540x; 1.0540x over previous
//
#include <hip/hip_runtime.h>
#include <math.h>

// BeliefPropagation collapse (round-0 derivation, verified absmax=0.0):
// h ∈ {0,1} is used as an INDEX by the reference, so only rows 0,1 of the
// message matrices are live; the iteration is a 12-scalar recurrence driven by
// cnt1[v] = sum_e h[e,v], n1[c] = sum_j h[c,j] (c∈{0,1}), base, w[:,0:2], sign.
//
// Round-3 change: replace libm tanhf/atanhf/expf + pow-by-squaring with
// hardware-pipe fast intrinsics (__expf/__logf/__powf). The serial thread-0
// recurrence was ~60-70 libm transcendentals with zero ILP (~6-10 us);
// fast versions are ~10-20 cy each (accuracy irrelevant at 1.4e-2 threshold).

#define V_N 512
#define E_N 256
#define BLK1 32            // k1 blocks; each handles E_N/BLK1 = 8 rows

__device__ inline float tanh_f(float x) {
    float xx = fminf(fmaxf(2.0f * x, -80.0f), 80.0f);
    float e = __expf(xx);
    return __fdividef(e - 1.0f, e + 1.0f);
}
__device__ inline float atanh_f(float x) {
    return 0.5f * __logf(__fdividef(1.0f + x, 1.0f - x));
}
__device__ inline float powi_f(float t, int n) {
    // t in (-1,1); t^n via fast pow on |t|, sign fixed for odd n.
    if (n <= 0) return 1.0f;
    float p = __powf(fabsf(t), (float)n);
    if ((n & 1) && t < 0.0f) p = -p;
    return p;
}

__global__ __launch_bounds__(256) void bp_count(const int* __restrict__ h,
                                                int* __restrict__ ws) {
    const int b = blockIdx.x, t = threadIdx.x;
    const int cg = t & 127;          // column group: cols 4cg..4cg+3
    const int rh = t >> 7;           // row half within block: 4 rows each
    const int4* h4 = (const int4*)h; // [E_N][V_N/4]
    const int rowbase = b * 8 + rh * 4;
    int4 acc = make_int4(0, 0, 0, 0);
    #pragma unroll
    for (int r = 0; r < 4; ++r) {
        int4 x = h4[(rowbase + r) * (V_N / 4) + cg];
        acc.x += x.x; acc.y += x.y; acc.z += x.z; acc.w += x.w;
    }
    __shared__ int4 p[2][128];
    p[rh][cg] = acc;
    __syncthreads();
    if (t < 128) {
        int4 a = p[0][t], c = p[1][t];
        ((int4*)ws)[b * 128 + t] =
            make_int4(a.x + c.x, a.y + c.y, a.z + c.z, a.w + c.w);
    }
}

__global__ __launch_bounds__(512) void bp_solve(
    const float* __restrict__ l_v, const int* __restrict__ h,
    const float* __restrict__ s_c, const float* __restrict__ b,
    const float* __restrict__ w, const int* __restrict__ it_p,
    const int* __restrict__ ws, float* __restrict__ out)
{
    const int v = threadIdx.x;       // 0..511, one thread per node

    __shared__ int cntsh[V_N];
    __shared__ int wred[8][2];
    __shared__ float csh[8];

    // ---- combine k1 partials: cnt1[v] = sum_b ws[b*512+v] (coalesced)
    int cnt = 0;
    #pragma unroll
    for (int bb = 0; bb < BLK1; ++bb)
        cnt += ws[bb * V_N + v];
    cntsh[v] = cnt;

    // ---- row sums n1[0], n1[1]: rows 0,1 of h; wave-shuffle reduce
    int r0 = h[v], r1 = h[V_N + v];
    #pragma unroll
    for (int off = 32; off > 0; off >>= 1) {
        r0 += __shfl_down(r0, off);
        r1 += __shfl_down(r1, off);
    }
    if ((v & 63) == 0) { wred[v >> 6][0] = r0; wred[v >> 6][1] = r1; }
    __syncthreads();

    // ---- 12-scalar recurrence (thread 0), fast transcendentals
    if (v == 0) {
        int n1_0 = 0, n1_1 = 0;
        #pragma unroll
        for (int wv = 0; wv < 8; ++wv) { n1_0 += wred[wv][0]; n1_1 += wred[wv][1]; }
        const int iters = it_p[0];
        const int n0_0 = V_N - n1_0, n0_1 = V_N - n1_1;
        const int cnt1_0 = cntsh[0], cnt1_1 = cntsh[1];
        const int cnt0_0 = E_N - cnt1_0, cnt0_1 = E_N - cnt1_1;
        const float base0 = l_v[0] * b[0];
        const float base1 = l_v[1] * b[1];
        const float w00 = w[0],     w01 = w[1];          // w[0,0], w[0,1]
        const float w10 = w[E_N],   w11 = w[E_N + 1];    // w[1,0], w[1,1]
        const float sg0 = 1.0f - 2.0f * s_c[0];
        const float sg1 = 1.0f - 2.0f * s_c[1];

        float V0c0 = 0.f, V0c1 = 0.f, V1c0 = 0.f, V1c1 = 0.f;
        float C0v0 = 0.f, C0v1 = 0.f, C0vR = 0.f;
        float C1v0 = 0.f, C1v1 = 0.f, C1vR = 0.f;

        for (int it = 0; it < iters; ++it) {
            // v->c (reads OLD mu_cv); total - sub0 = T1, total - sub1 = T0
            float T0 = (float)cnt0_0 * C0v0 * w00;
            float T1 = (float)cnt1_0 * C1v0 * w01;
            float nV0c0 = tanh_f(0.5f * (base0 + T1));
            float nV0c1 = tanh_f(0.5f * (base0 + T0));
            T0 = (float)cnt0_1 * C0v1 * w10;
            T1 = (float)cnt1_1 * C1v1 * w11;
            float nV1c0 = tanh_f(0.5f * (base1 + T1));
            float nV1c1 = tanh_f(0.5f * (base1 + T0));

            // c->v (reads OLD mu_vc — Jacobi, matches reference)
            float t0 = tanh_f(0.5f * V0c0);
            float t1 = tanh_f(0.5f * V1c0);
            float p0 = powi_f(t0, n0_0);
            float p1 = powi_f(t1, n1_0);
            float nC0v0 = sg0 * 2.0f * atanh_f(p1);
            float nC0v1 = sg0 * 2.0f * atanh_f(p0);
            float nC0vR = sg0 * 2.0f * atanh_f(p0 * p1);
            t0 = tanh_f(0.5f * V0c1);
            t1 = tanh_f(0.5f * V1c1);
            p0 = powi_f(t0, n0_1);
            p1 = powi_f(t1, n1_1);
            float nC1v0 = sg1 * 2.0f * atanh_f(p1);
            float nC1v1 = sg1 * 2.0f * atanh_f(p0);
            float nC1vR = sg1 * 2.0f * atanh_f(p0 * p1);

            V0c0 = nV0c0; V0c1 = nV0c1; V1c0 = nV1c0; V1c1 = nV1c1;
            C0v0 = nC0v0; C0v1 = nC0v1; C0vR = nC0vR;
            C1v0 = nC1v0; C1v1 = nC1v1; C1vR = nC1vR;
        }
        csh[0] = C0v0; csh[1] = C0v1; csh[2] = C0vR;
        csh[3] = C1v0; csh[4] = C1v1; csh[5] = C1vR;
    }
    __syncthreads();

    // ---- marginalization + output
    {
        const int cnt1 = cntsh[v];
        const int cnt0 = E_N - cnt1;
        const float basev = l_v[v] * b[v];
        const float wv0 = w[v * E_N + 0];
        const float wv1 = w[v * E_N + 1];
        const float c0 = (v == 0) ? csh[0] : (v == 1) ? csh[1] : csh[2];
        const float c1 = (v == 0) ? csh[3] : (v == 1) ? csh[4] : csh[5];
        const float s = basev + (float)cnt0 * c0 * wv0 + (float)cnt1 * c1 * wv1;
        const float mu = tanh_f(0.5f * s);
        out[v] = __fdividef(1.0f, __expf(mu) + 1.0f);
    }
}

extern "C" void kernel_launch(void* const* d_in, const int* in_sizes, int n_in,
                              void* d_out, int out_size, void* d_ws, size_t ws_size,
                              hipStream_t stream) {
    const float* l_v   = (const float*)d_in[0];
    const int*   h     = (const int*)  d_in[1];
    const float* s_c   = (const float*)d_in[2];
    const float* b     = (const float*)d_in[3];
    const float* w     = (const float*)d_in[4];
    const int*   iters = (const int*)  d_in[5];
    float* out = (float*)d_out;
    int*   ws  = (int*)d_ws;

    hipLaunchKernelGGL(bp_count, dim3(BLK1), dim3(256), 0, stream, h, ws);
    hipLaunchKernelGGL(bp_solve, dim3(1), dim3(512), 0, stream,
                       l_v, h, s_c, b, w, iters, ws, out);
}

// Round 4
// 22.734 us; speedup vs baseline: 1.0675x; 1.0128x over previous
//
#include <hip/hip_runtime.h>
#include <math.h>

// BeliefPropagation collapse (round-0 derivation, verified absmax=0.0):
// h ∈ {0,1} is used as an INDEX by the reference, so only rows 0,1 of the
// message matrices are live; the iteration is a 12-scalar recurrence driven by
// cnt1[v] = sum_e h[e,v], n1[c] = sum_j h[c,j] (c∈{0,1}), base, w[:,0:2], sign.
//
// Round-4 change: SINGLE dispatch. 32 blocks count h columns (8 rows each,
// int4 loads); each block release-fences and sets a flag in d_ws; block 0
// spin-waits on all 32 flags (device-scope atomics), acquire-fences, reduces
// the partials, runs the fast-intrinsic recurrence, writes out[512], and
// resets the flags to 0 (deterministic across graph replays; first call after
// the 0xAA poison works because the spin tests ==1 and 0xAAAAAAAA != 1).

#define V_N 512
#define E_N 256
#define NBLK 32

__device__ inline float tanh_f(float x) {
    float xx = fminf(fmaxf(2.0f * x, -80.0f), 80.0f);
    float e = __expf(xx);
    return __fdividef(e - 1.0f, e + 1.0f);
}
__device__ inline float atanh_f(float x) {
    return 0.5f * __logf(__fdividef(1.0f + x, 1.0f - x));
}
__device__ inline float powi_f(float t, int n) {
    if (n <= 0) return 1.0f;
    float p = __powf(fabsf(t), (float)n);
    if ((n & 1) && t < 0.0f) p = -p;
    return p;
}

__global__ __launch_bounds__(256) void bp_fused(
    const float* __restrict__ l_v, const int* __restrict__ h,
    const float* __restrict__ s_c, const float* __restrict__ b_,
    const float* __restrict__ w, const int* __restrict__ it_p,
    int* ws, float* __restrict__ out)
{
    const int blk = blockIdx.x, t = threadIdx.x;
    int* flags = ws + NBLK * V_N;   // 32 flag words after the partials

    // ---- phase 1: per-block column counts over 8 rows of h (int4 loads)
    {
        const int cg = t & 127;          // column group: cols 4cg..4cg+3
        const int rh = t >> 7;           // row half: 4 rows each
        const int4* h4 = (const int4*)h; // [E_N][V_N/4]
        const int rowbase = blk * 8 + rh * 4;
        int4 acc = make_int4(0, 0, 0, 0);
        #pragma unroll
        for (int r = 0; r < 4; ++r) {
            int4 x = h4[(rowbase + r) * (V_N / 4) + cg];
            acc.x += x.x; acc.y += x.y; acc.z += x.z; acc.w += x.w;
        }
        __shared__ int4 p[2][128];
        p[rh][cg] = acc;
        __syncthreads();
        if (t < 128) {
            int4 a = p[0][t], c = p[1][t];
            ((int4*)ws)[blk * 128 + t] =
                make_int4(a.x + c.x, a.y + c.y, a.z + c.z, a.w + c.w);
        }
    }
    __threadfence();                 // release: partials visible device-wide
    __syncthreads();
    if (t == 0) atomicExch(&flags[blk], 1);
    if (blk != 0) return;

    // ---- phase 2 (block 0 only): wait for all partials
    if (t < NBLK) {
        while (atomicAdd(&flags[t], 0) != 1) { }
    }
    __syncthreads();
    __threadfence();                 // acquire

    __shared__ int cntsh[V_N];
    __shared__ int wred[4][2];
    __shared__ float csh[8];

    // combine partials: thread t handles columns t and t+256
    int c0s = 0, c1s = 0;
    #pragma unroll
    for (int bb = 0; bb < NBLK; ++bb) {
        c0s += ws[bb * V_N + t];
        c1s += ws[bb * V_N + t + 256];
    }
    cntsh[t] = c0s;
    cntsh[t + 256] = c1s;

    // row sums n1[0], n1[1] of h rows 0,1 (4 KB, L2-hot): 2 cols/thread
    int r0 = h[t] + h[t + 256];
    int r1 = h[V_N + t] + h[V_N + t + 256];
    #pragma unroll
    for (int off = 32; off > 0; off >>= 1) {
        r0 += __shfl_down(r0, off);
        r1 += __shfl_down(r1, off);
    }
    if ((t & 63) == 0) { wred[t >> 6][0] = r0; wred[t >> 6][1] = r1; }
    __syncthreads();

    // ---- 12-scalar recurrence (thread 0), fast transcendentals
    if (t == 0) {
        int n1_0 = 0, n1_1 = 0;
        #pragma unroll
        for (int wv = 0; wv < 4; ++wv) { n1_0 += wred[wv][0]; n1_1 += wred[wv][1]; }
        const int iters = it_p[0];
        const int n0_0 = V_N - n1_0, n0_1 = V_N - n1_1;
        const int cnt1_0 = cntsh[0], cnt1_1 = cntsh[1];
        const int cnt0_0 = E_N - cnt1_0, cnt0_1 = E_N - cnt1_1;
        const float base0 = l_v[0] * b_[0];
        const float base1 = l_v[1] * b_[1];
        const float w00 = w[0],     w01 = w[1];          // w[0,0], w[0,1]
        const float w10 = w[E_N],   w11 = w[E_N + 1];    // w[1,0], w[1,1]
        const float sg0 = 1.0f - 2.0f * s_c[0];
        const float sg1 = 1.0f - 2.0f * s_c[1];

        float V0c0 = 0.f, V0c1 = 0.f, V1c0 = 0.f, V1c1 = 0.f;
        float C0v0 = 0.f, C0v1 = 0.f, C0vR = 0.f;
        float C1v0 = 0.f, C1v1 = 0.f, C1vR = 0.f;

        for (int it = 0; it < iters; ++it) {
            // v->c (reads OLD mu_cv); total - sub0 = T1, total - sub1 = T0
            float T0 = (float)cnt0_0 * C0v0 * w00;
            float T1 = (float)cnt1_0 * C1v0 * w01;
            float nV0c0 = tanh_f(0.5f * (base0 + T1));
            float nV0c1 = tanh_f(0.5f * (base0 + T0));
            T0 = (float)cnt0_1 * C0v1 * w10;
            T1 = (float)cnt1_1 * C1v1 * w11;
            float nV1c0 = tanh_f(0.5f * (base1 + T1));
            float nV1c1 = tanh_f(0.5f * (base1 + T0));

            // c->v (reads OLD mu_vc — Jacobi, matches reference)
            float t0 = tanh_f(0.5f * V0c0);
            float t1 = tanh_f(0.5f * V1c0);
            float p0 = powi_f(t0, n0_0);
            float p1 = powi_f(t1, n1_0);
            float nC0v0 = sg0 * 2.0f * atanh_f(p1);
            float nC0v1 = sg0 * 2.0f * atanh_f(p0);
            float nC0vR = sg0 * 2.0f * atanh_f(p0 * p1);
            t0 = tanh_f(0.5f * V0c1);
            t1 = tanh_f(0.5f * V1c1);
            p0 = powi_f(t0, n0_1);
            p1 = powi_f(t1, n1_1);
            float nC1v0 = sg1 * 2.0f * atanh_f(p1);
            float nC1v1 = sg1 * 2.0f * atanh_f(p0);
            float nC1vR = sg1 * 2.0f * atanh_f(p0 * p1);

            V0c0 = nV0c0; V0c1 = nV0c1; V1c0 = nV1c0; V1c1 = nV1c1;
            C0v0 = nC0v0; C0v1 = nC0v1; C0vR = nC0vR;
            C1v0 = nC1v0; C1v1 = nC1v1; C1vR = nC1vR;
        }
        csh[0] = C0v0; csh[1] = C0v1; csh[2] = C0vR;
        csh[3] = C1v0; csh[4] = C1v1; csh[5] = C1vR;
    }
    __syncthreads();

    // ---- marginalization + output: thread t writes v = t and t+256
    #pragma unroll
    for (int k = 0; k < 2; ++k) {
        const int v = t + k * 256;
        const int cnt1 = cntsh[v];
        const int cnt0 = E_N - cnt1;
        const float basev = l_v[v] * b_[v];
        const float wv0 = w[v * E_N + 0];
        const float wv1 = w[v * E_N + 1];
        const float c0 = (v == 0) ? csh[0] : (v == 1) ? csh[1] : csh[2];
        const float c1 = (v == 0) ? csh[3] : (v == 1) ? csh[4] : csh[5];
        const float s = basev + (float)cnt0 * c0 * wv0 + (float)cnt1 * c1 * wv1;
        const float mu = tanh_f(0.5f * s);
        out[v] = __fdividef(1.0f, __expf(mu) + 1.0f);
    }

    // ---- reset flags so every replay starts from the same state
    if (t < NBLK) atomicExch(&flags[t], 0);
}

extern "C" void kernel_launch(void* const* d_in, const int* in_sizes, int n_in,
                              void* d_out, int out_size, void* d_ws, size_t ws_size,
                              hipStream_t stream) {
    const float* l_v   = (const float*)d_in[0];
    const int*   h     = (const int*)  d_in[1];
    const float* s_c   = (const float*)d_in[2];
    const float* b     = (const float*)d_in[3];
    const float* w     = (const float*)d_in[4];
    const int*   iters = (const int*)  d_in[5];
    float* out = (float*)d_out;
    int*   ws  = (int*)d_ws;

    hipLaunchKernelGGL(bp_fused, dim3(NBLK), dim3(256), 0, stream,
                       l_v, h, s_c, b, w, iters, ws, out);
}

// Round 5
// 21.931 us; speedup vs baseline: 1.1066x; 1.0366x over previous
//
#include <hip/hip_runtime.h>
#include <math.h>

// BeliefPropagation collapse (round-0 derivation, verified absmax=0.0):
// h ∈ {0,1} is used as an INDEX by the reference, so only rows 0,1 of the
// message matrices are live; the iteration is a 12-scalar recurrence driven by
// cnt1[v] = sum_e h[e,v], n1[c] = sum_j h[c,j] (c∈{0,1}), base, w[:,0:2], sign.
//
// Round-5 change: floor-discriminator. SINGLE block, 1024 threads, int4
// loads (32 per thread), no d_ws, no inter-block handshake, fast
// transcendentals. If dur_us stays ~23 us, the measurement is per-replay
// fixed overhead and the kernel is done (real GPU work ~2-3 us).

#define V_N 512
#define E_N 256

__device__ inline float tanh_f(float x) {
    float xx = fminf(fmaxf(2.0f * x, -80.0f), 80.0f);
    float e = __expf(xx);
    return __fdividef(e - 1.0f, e + 1.0f);
}
__device__ inline float atanh_f(float x) {
    return 0.5f * __logf(__fdividef(1.0f + x, 1.0f - x));
}
__device__ inline float powi_f(float t, int n) {
    if (n <= 0) return 1.0f;
    float p = __powf(fabsf(t), (float)n);
    if ((n & 1) && t < 0.0f) p = -p;
    return p;
}

__global__ __launch_bounds__(1024) void bp_one(
    const float* __restrict__ l_v, const int* __restrict__ h,
    const float* __restrict__ s_c, const float* __restrict__ b_,
    const float* __restrict__ w, const int* __restrict__ it_p,
    float* __restrict__ out)
{
    const int t = threadIdx.x;
    const int cg = t & 127;          // column group: cols 4cg..4cg+3
    const int rh = t >> 7;           // row chunk: 32 rows each (8 chunks)

    __shared__ int4 p[8][128];       // per-chunk column partials (16 KB)
    __shared__ int cntsh[V_N];
    __shared__ int wred[16][2];
    __shared__ float csh[8];

    // ---- column counts: 32 int4 rows per thread, all in flight-able
    {
        const int4* h4 = (const int4*)h;  // [E_N][V_N/4]
        int4 acc = make_int4(0, 0, 0, 0);
        const int rowbase = rh * 32;
        #pragma unroll 8
        for (int r = 0; r < 32; ++r) {
            int4 x = h4[(rowbase + r) * (V_N / 4) + cg];
            acc.x += x.x; acc.y += x.y; acc.z += x.z; acc.w += x.w;
        }
        p[rh][cg] = acc;
    }

    // ---- row sums of h rows 0,1 (first 1024 ints = exactly one per thread)
    // element t of row 0 is h[t] for t<512; element t-512 of row 1 otherwise.
    {
        int x = h[t];                // rows 0..1 concatenated
        #pragma unroll
        for (int off = 32; off > 0; off >>= 1) x += __shfl_down(x, off);
        if ((t & 63) == 0) { wred[t >> 6][0] = x; wred[t >> 6][1] = 0; }
    }
    __syncthreads();

    // ---- reduce chunk partials: threads 0..127 sum 8 int4s
    if (t < 128) {
        int4 s = make_int4(0, 0, 0, 0);
        #pragma unroll
        for (int r = 0; r < 8; ++r) {
            int4 x = p[r][t];
            s.x += x.x; s.y += x.y; s.z += x.z; s.w += x.w;
        }
        cntsh[4 * t + 0] = s.x;
        cntsh[4 * t + 1] = s.y;
        cntsh[4 * t + 2] = s.z;
        cntsh[4 * t + 3] = s.w;
    }
    __syncthreads();

    // ---- 12-scalar recurrence (thread 0), fast transcendentals
    if (t == 0) {
        int n1_0 = 0, n1_1 = 0;
        #pragma unroll
        for (int wv = 0; wv < 8; ++wv)  n1_0 += wred[wv][0];   // waves 0..7: row 0
        #pragma unroll
        for (int wv = 8; wv < 16; ++wv) n1_1 += wred[wv][0];   // waves 8..15: row 1
        const int iters = it_p[0];
        const int n0_0 = V_N - n1_0, n0_1 = V_N - n1_1;
        const int cnt1_0 = cntsh[0], cnt1_1 = cntsh[1];
        const int cnt0_0 = E_N - cnt1_0, cnt0_1 = E_N - cnt1_1;
        const float base0 = l_v[0] * b_[0];
        const float base1 = l_v[1] * b_[1];
        const float w00 = w[0],     w01 = w[1];          // w[0,0], w[0,1]
        const float w10 = w[E_N],   w11 = w[E_N + 1];    // w[1,0], w[1,1]
        const float sg0 = 1.0f - 2.0f * s_c[0];
        const float sg1 = 1.0f - 2.0f * s_c[1];

        float V0c0 = 0.f, V0c1 = 0.f, V1c0 = 0.f, V1c1 = 0.f;
        float C0v0 = 0.f, C0v1 = 0.f, C0vR = 0.f;
        float C1v0 = 0.f, C1v1 = 0.f, C1vR = 0.f;

        for (int it = 0; it < iters; ++it) {
            // v->c (reads OLD mu_cv); total - sub0 = T1, total - sub1 = T0
            float T0 = (float)cnt0_0 * C0v0 * w00;
            float T1 = (float)cnt1_0 * C1v0 * w01;
            float nV0c0 = tanh_f(0.5f * (base0 + T1));
            float nV0c1 = tanh_f(0.5f * (base0 + T0));
            T0 = (float)cnt0_1 * C0v1 * w10;
            T1 = (float)cnt1_1 * C1v1 * w11;
            float nV1c0 = tanh_f(0.5f * (base1 + T1));
            float nV1c1 = tanh_f(0.5f * (base1 + T0));

            // c->v (reads OLD mu_vc — Jacobi, matches reference)
            float t0 = tanh_f(0.5f * V0c0);
            float t1 = tanh_f(0.5f * V1c0);
            float p0 = powi_f(t0, n0_0);
            float p1 = powi_f(t1, n1_0);
            float nC0v0 = sg0 * 2.0f * atanh_f(p1);
            float nC0v1 = sg0 * 2.0f * atanh_f(p0);
            float nC0vR = sg0 * 2.0f * atanh_f(p0 * p1);
            t0 = tanh_f(0.5f * V0c1);
            t1 = tanh_f(0.5f * V1c1);
            p0 = powi_f(t0, n0_1);
            p1 = powi_f(t1, n1_1);
            float nC1v0 = sg1 * 2.0f * atanh_f(p1);
            float nC1v1 = sg1 * 2.0f * atanh_f(p0);
            float nC1vR = sg1 * 2.0f * atanh_f(p0 * p1);

            V0c0 = nV0c0; V0c1 = nV0c1; V1c0 = nV1c0; V1c1 = nV1c1;
            C0v0 = nC0v0; C0v1 = nC0v1; C0vR = nC0vR;
            C1v0 = nC1v0; C1v1 = nC1v1; C1vR = nC1vR;
        }
        csh[0] = C0v0; csh[1] = C0v1; csh[2] = C0vR;
        csh[3] = C1v0; csh[4] = C1v1; csh[5] = C1vR;
    }
    __syncthreads();

    // ---- marginalization + output (threads 0..511)
    if (t < V_N) {
        const int v = t;
        const int cnt1 = cntsh[v];
        const int cnt0 = E_N - cnt1;
        const float basev = l_v[v] * b_[v];
        const float wv0 = w[v * E_N + 0];
        const float wv1 = w[v * E_N + 1];
        const float c0 = (v == 0) ? csh[0] : (v == 1) ? csh[1] : csh[2];
        const float c1 = (v == 0) ? csh[3] : (v == 1) ? csh[4] : csh[5];
        const float s = basev + (float)cnt0 * c0 * wv0 + (float)cnt1 * c1 * wv1;
        const float mu = tanh_f(0.5f * s);
        out[v] = __fdividef(1.0f, __expf(mu) + 1.0f);
    }
}

extern "C" void kernel_launch(void* const* d_in, const int* in_sizes, int n_in,
                              void* d_out, int out_size, void* d_ws, size_t ws_size,
                              hipStream_t stream) {
    const float* l_v   = (const float*)d_in[0];
    const int*   h     = (const int*)  d_in[1];
    const float* s_c   = (const float*)d_in[2];
    const float* b     = (const float*)d_in[3];
    const float* w     = (const float*)d_in[4];
    const int*   iters = (const int*)  d_in[5];
    float* out = (float*)d_out;

    hipLaunchKernelGGL(bp_one, dim3(1), dim3(1024), 0, stream,
                       l_v, h, s_c, b, w, iters, out);
}